// Round 13
// baseline (276.261 us; speedup 1.0000x reference)
//
#include <hip/hip_runtime.h>
#include <hip/hip_fp16.h>
#include <hip/hip_cooperative_groups.h>
#include <math.h>

namespace cg = cooperative_groups;

__device__ __forceinline__ float sigm(float x)  { return 1.0f / (1.0f + __expf(-x)); }
__device__ __forceinline__ float siluf(float x) { return x * sigm(x); }

typedef _Float16 half8  __attribute__((ext_vector_type(8)));
typedef _Float16 half4  __attribute__((ext_vector_type(4)));
typedef float    f32x4  __attribute__((ext_vector_type(4)));
typedef unsigned u32x2  __attribute__((ext_vector_type(2)));

// async global->LDS, 16 B/lane: LDS dest = wave-uniform base + lane*16 (packed!)
__device__ __forceinline__ void gld16(const void* g, void* l) {
    __builtin_amdgcn_global_load_lds(
        (const __attribute__((address_space(1))) unsigned*)g,
        (__attribute__((address_space(3))) unsigned*)l, 16, 0, 0);
}

template <int N>
__device__ __forceinline__ void wait_vmcnt() {
    if constexpr (N == 0)      asm volatile("s_waitcnt vmcnt(0)" ::: "memory");
    else if constexpr (N == 3) asm volatile("s_waitcnt vmcnt(3)" ::: "memory");
    else if constexpr (N == 5) asm volatile("s_waitcnt vmcnt(5)" ::: "memory");
    else if constexpr (N == 6) asm volatile("s_waitcnt vmcnt(6)" ::: "memory");
}

// =======================================================================
// 2-term split GEMM core (R9/R16 form: 2-buf counted-vmcnt, k-stagger).
// Session local optimum; unchanged.
// =======================================================================
template <int MI, int AMODE>
__device__ __forceinline__ void gemm_core16(
    const __half* __restrict__ A16,
    const __half* __restrict__ Bhi, const __half* __restrict__ Blo,
    int nbs, int m0, int n0, int t, int koff, f32x4 (&acc)[MI][4])
{
    __shared__ short As[2][MI * 1024], BsHi[2][4096], BsLo[2][4096];
    const int lane = t & 63, wave = t >> 6;
    const int wm = (wave >> 1) * (MI << 4), wn = (wave & 1) << 6;
    const int fr = lane & 15, fq = lane >> 4;
    constexpr int NL = MI / 2 + 4;         // gld16s per wave per stage

    auto stage = [&](int kb, int buf) {
        const int kc = (kb + koff) & 7;    // staggered k-slice
#pragma unroll
        for (int hf = 0; hf < MI / 2; ++hf) {          // A: MI*8 rows/wave
            const int rr = wave * (MI << 3) + (hf << 4);
            size_t ga;
            if (AMODE == 0)
                ga = (((size_t)(kc * 8192 + m0 + rr)) << 5) + (lane << 3);
            else
                ga = (((size_t)(m0 + rr + (lane >> 2))) << 8) + (kc << 5) + ((lane & 3) << 3);
            gld16(A16 + ga, &As[buf][rr << 5]);
        }
#pragma unroll
        for (int hf = 0; hf < 2; ++hf) {               // B: 32 rows/wave
            const int rr = (wave << 5) + (hf << 4);
            const size_t gb = (((size_t)(kc * nbs + n0 + rr)) << 5) + (lane << 3);
            gld16(Bhi + gb, &BsHi[buf][rr << 5]);
            gld16(Blo + gb, &BsLo[buf][rr << 5]);
        }
    };

    stage(0, 0);
#pragma unroll
    for (int kb = 0; kb < 8; ++kb) {
        const int cur = kb & 1;
        if (kb < 7) {
            stage(kb + 1, cur ^ 1);        // NL loads now in flight
            wait_vmcnt<NL>();              // tile-k loads complete
        } else {
            wait_vmcnt<0>();
        }
        __builtin_amdgcn_s_barrier();      // all waves' tile-k writes visible

        half8 a[MI], bh[4], bl[4];
#pragma unroll
        for (int i = 0; i < MI; ++i)
            a[i] = *(const half8*)&As[cur][((wm + (i << 4) + fr) << 5) + (fq << 3)];
#pragma unroll
        for (int i = 0; i < 4; ++i) {
            const int boff = ((wn + (i << 4) + fr) << 5) + (fq << 3);
            bh[i] = *(const half8*)&BsHi[cur][boff];
            bl[i] = *(const half8*)&BsLo[cur][boff];
        }
#pragma unroll
        for (int mi = 0; mi < MI; ++mi)
#pragma unroll
            for (int ni = 0; ni < 4; ++ni) {
                acc[mi][ni] = __builtin_amdgcn_mfma_f32_16x16x32_f16(a[mi], bh[ni], acc[mi][ni], 0, 0, 0);
                acc[mi][ni] = __builtin_amdgcn_mfma_f32_16x16x32_f16(a[mi], bl[ni], acc[mi][ni], 0, 0, 0);
            }

        if (kb < 7) __builtin_amdgcn_s_barrier();
    }
}

// =======================================================================
// 64x64-tile core on caller LDS (As[2][2048]|BsHi[2][2048]|BsLo[2][2048]
// = 12288 shorts).  R9 2-buf counted-vmcnt + k-stagger, unchanged math.
// =======================================================================
__device__ __forceinline__ void gemm_core64_lds(
    short* lds,
    const __half* __restrict__ A16,
    const __half* __restrict__ Bhi, const __half* __restrict__ Blo,
    int m0, int n0, int t, int koff, f32x4 (&acc)[4])
{
    short* As   = lds;
    short* BsHi = lds + 4096;
    short* BsLo = lds + 8192;
    const int lane = t & 63, wave = t >> 6;
    const int wm = wave << 4;
    const int fr = lane & 15, fq = lane >> 4;

    auto stage = [&](int kb, int buf) {
        const int kc = (kb + koff) & 7;
        const int rr = wave << 4;          // 16 rows/wave (A and B)
        const size_t ga = (((size_t)(m0 + rr + (lane >> 2))) << 8) + (kc << 5) + ((lane & 3) << 3);
        gld16(A16 + ga, &As[buf * 2048 + (rr << 5)]);
        const size_t gb = (((size_t)(kc * 256 + n0 + rr)) << 5) + (lane << 3);
        gld16(Bhi + gb, &BsHi[buf * 2048 + (rr << 5)]);
        gld16(Blo + gb, &BsLo[buf * 2048 + (rr << 5)]);
    };

    stage(0, 0);
#pragma unroll
    for (int kb = 0; kb < 8; ++kb) {
        const int cur = kb & 1;
        if (kb < 7) {
            stage(kb + 1, cur ^ 1);
            wait_vmcnt<3>();
        } else {
            wait_vmcnt<0>();
        }
        __builtin_amdgcn_s_barrier();

        half8 a = *(const half8*)&As[cur * 2048 + ((wm + fr) << 5) + (fq << 3)];
        half8 bh[4], bl[4];
#pragma unroll
        for (int ni = 0; ni < 4; ++ni) {
            const int boff = (((ni << 4) + fr) << 5) + (fq << 3);
            bh[ni] = *(const half8*)&BsHi[cur * 2048 + boff];
            bl[ni] = *(const half8*)&BsLo[cur * 2048 + boff];
        }
#pragma unroll
        for (int ni = 0; ni < 4; ++ni) {
            acc[ni] = __builtin_amdgcn_mfma_f32_16x16x32_f16(a, bh[ni], acc[ni], 0, 0, 0);
            acc[ni] = __builtin_amdgcn_mfma_f32_16x16x32_f16(a, bl[ni], acc[ni], 0, 0, 0);
        }

        if (kb < 7) __builtin_amdgcn_s_barrier();
    }
}

// =======================================================================
// Prep (R20 form): x -> f16 k-blocked + wp; weights -> [kb][n][32] hi/lo.
// =======================================================================
__global__ __launch_bounds__(256) void prep_kernel(
    const float* __restrict__ x, const float* __restrict__ Wqkv,
    const float* __restrict__ Wgate, const float* __restrict__ Wout,
    const float* __restrict__ Wwp, const float* __restrict__ bwp,
    __half* __restrict__ xh,
    __half* __restrict__ wqh, __half* __restrict__ wql,
    __half* __restrict__ wgh, __half* __restrict__ wgl,
    __half* __restrict__ woh, __half* __restrict__ wol,
    float* __restrict__ width, float* __restrict__ sharp)
{
    __shared__ float xs[32][260];
    const int t = threadIdx.x;
    const int blk = blockIdx.x;
    if (blk < 256) {
        const int row0 = blk << 5;
        for (int e = t; e < 2048; e += 256) {
            int r = e >> 6, cc = (e & 63) << 2;
            *(float4*)&xs[r][cc] = *(const float4*)&x[(size_t)(row0 + r) * 256 + cc];
        }
        __syncthreads();
        const int r = t & 31, kb = t >> 5;
        __half hibuf[32];
#pragma unroll
        for (int i = 0; i < 32; ++i)
            hibuf[i] = __float2half(xs[r][(kb << 5) + i]);
        const size_t ob = ((size_t)(kb * 8192 + row0 + r)) << 5;
#pragma unroll
        for (int i = 0; i < 4; ++i)
            *(int4*)&xh[ob + (i << 3)] = *(int4*)&hibuf[i << 3];
        // wp: thread (r, n=kb); 4 accumulators break the 256-FMA dep chain
        float a0 = 0.f, a1 = 0.f, a2 = 0.f, a3 = 0.f;
#pragma unroll 4
        for (int k = 0; k < 256; k += 4) {
            a0 += xs[r][k + 0] * Wwp[(k + 0) * 8 + kb];
            a1 += xs[r][k + 1] * Wwp[(k + 1) * 8 + kb];
            a2 += xs[r][k + 2] * Wwp[(k + 2) * 8 + kb];
            a3 += xs[r][k + 3] * Wwp[(k + 3) * 8 + kb];
        }
        const float acc = (a0 + a1) + (a2 + a3);
        float s = sigm(siluf(acc + bwp[kb]));
        const int row = row0 + r;
        if (kb < 4) width[row * 4 + kb] = s * 4.242640687119285f + 0.5f;  // sqrt(18)
        else        sharp[row * 4 + kb - 4] = s * 9.5f + 0.5f;
    } else {
        const float* W; __half *Whi, *Wlo; int N, nb0, ncnt;
        if (blk < 288)      { W = Wqkv;  Whi = wqh; Wlo = wql; N = 768; nb0 = (blk - 256) * 24; ncnt = 24; }
        else if (blk < 296) { W = Wgate; Whi = wgh; Wlo = wgl; N = 256; nb0 = (blk - 288) * 32; ncnt = 32; }
        else                { W = Wout;  Whi = woh; Wlo = wol; N = 256; nb0 = (blk - 296) * 32; ncnt = 32; }
        for (int j = 0; j < ncnt; ++j)
            xs[j][t] = W[(size_t)t * N + nb0 + j];   // t = k row
        __syncthreads();
        for (int c = t; c < ncnt * 8; c += 256) {
            const int j = c >> 3, kb = c & 7;
            __half hibuf[32], lobuf[32];
#pragma unroll
            for (int i = 0; i < 32; ++i) {
                float v = xs[j][(kb << 5) + i];
                __half hv = __float2half(v);
                hibuf[i] = hv;
                lobuf[i] = __float2half(v - __half2float(hv));
            }
            const size_t ob = ((size_t)(kb * N + nb0 + j)) << 5;
#pragma unroll
            for (int i = 0; i < 4; ++i) {
                *(int4*)&Whi[ob + (i << 3)] = *(int4*)&hibuf[i << 3];
                *(int4*)&Wlo[ob + (i << 3)] = *(int4*)&lobuf[i << 3];
            }
        }
    }
}

// =======================================================================
// qkv GEMM (64x128 tiles, 768 blocks = 3/CU, k-staggered) + fused silu ->
// rmsnorm -> RoPE(pos=head) -> f16 stores.  Unchanged.
// =======================================================================
__global__ __launch_bounds__(256, 3) void gemm_qkv(
    const __half* __restrict__ xh,
    const __half* __restrict__ wqh, const __half* __restrict__ wql,
    const float* __restrict__ wq, const float* __restrict__ wk,
    __half* __restrict__ qh, __half* __restrict__ kh, __half* __restrict__ vh)
{
    const int t  = threadIdx.x;
    const int m0 = blockIdx.y << 6, n0 = blockIdx.x << 7;
    f32x4 acc[2][4] = {};
    gemm_core16<2, 0>(xh, wqh, wql, 768, m0, n0, t, blockIdx.y & 7, acc);

    const int lane = t & 63, wave = t >> 6;
    const int wm = (wave >> 1) << 5, wn = (wave & 1) << 6;
    const int fr = lane & 15, fq = lane >> 4;
    const int gc0 = n0 + wn;
    const int seg = gc0 >> 8;          // 0=q, 1=k, 2=v
    const int h   = (gc0 >> 6) & 3;
    const int hc0 = h << 6;

#pragma unroll
    for (int mi = 0; mi < 2; ++mi)
#pragma unroll
        for (int ni = 0; ni < 4; ++ni)
#pragma unroll
            for (int r = 0; r < 4; ++r)
                acc[mi][ni][r] = siluf(acc[mi][ni][r]);

    if (seg == 2) {
#pragma unroll
        for (int mi = 0; mi < 2; ++mi)
#pragma unroll
            for (int r = 0; r < 4; ++r) {
                const size_t row = m0 + wm + (mi << 4) + (fq << 2) + r;
#pragma unroll
                for (int ni = 0; ni < 4; ++ni)
                    vh[row * 256 + hc0 + (ni << 4) + fr] = __float2half(acc[mi][ni][r]);
            }
    } else {
        const float* wnorm = seg ? wk : wq;
        float wv[4];
#pragma unroll
        for (int ni = 0; ni < 4; ++ni) wv[ni] = wnorm[(ni << 4) + fr];
        float cs[2], sn[2];
#pragma unroll
        for (int j = 0; j < 2; ++j) {
            const int d = (j << 4) + fr;
            const float freq = powf(10000.f, -(float)d * (1.f / 32.f));
            const float ang = (float)h * freq;    // pos = arange(H) reference quirk
            cs[j] = cosf(ang); sn[j] = sinf(ang);
        }
        __half* dstbase = (seg ? kh : qh);
#pragma unroll
        for (int mi = 0; mi < 2; ++mi)
#pragma unroll
            for (int r = 0; r < 4; ++r) {
                float ss = acc[mi][0][r] * acc[mi][0][r] + acc[mi][1][r] * acc[mi][1][r]
                         + acc[mi][2][r] * acc[mi][2][r] + acc[mi][3][r] * acc[mi][3][r];
                ss += __shfl_xor(ss, 1); ss += __shfl_xor(ss, 2);
                ss += __shfl_xor(ss, 4); ss += __shfl_xor(ss, 8);
                const float rinv = 1.f / sqrtf(ss * (1.f / 64.f) + 1e-6f);
                float xv[4];
#pragma unroll
                for (int ni = 0; ni < 4; ++ni) xv[ni] = acc[mi][ni][r] * rinv * wv[ni];
                const float o0 = xv[0] * cs[0] - xv[2] * sn[0];
                const float o2 = xv[0] * sn[0] + xv[2] * cs[0];
                const float o1 = xv[1] * cs[1] - xv[3] * sn[1];
                const float o3 = xv[1] * sn[1] + xv[3] * cs[1];
                const size_t row = m0 + wm + (mi << 4) + (fq << 2) + r;
                __half* dst = dstbase + row * 256 + hc0;
                dst[fr]      = __float2half(o0);
                dst[16 + fr] = __float2half(o1);
                dst[32 + fr] = __float2half(o2);
                dst[48 + fr] = __float2half(o3);
            }
    }
}

// =======================================================================
// R21: cooperative fused gate+out.  512 blocks x 256 thr, 24 KB LDS ->
// guaranteed co-resident (2/CU).  Phase 1 = gate GEMM + merge -> mh
// (byte-identical to old gemm_gate); threadfence + grid.sync (device-
// scope release/acquire for cross-XCD mh visibility); phase 2 = out GEMM
// (byte-identical to old gemm_out, mh L2/LLC-warm).  Removes one launch
// boundary; inner loops untouched.
// =======================================================================
__global__ __launch_bounds__(256, 2) void gemm_gateout(
    const __half* __restrict__ vh,
    const __half* __restrict__ wgh, const __half* __restrict__ wgl,
    const float* __restrict__ bias, const float* __restrict__ attn_o,
    const float* __restrict__ sumsq4, const float* __restrict__ w_onorm,
    __half* __restrict__ mh,
    const __half* __restrict__ woh, const __half* __restrict__ wol,
    float* __restrict__ out)
{
    __shared__ short lds[12288];           // 24 KB, reused by both phases
    const int t = threadIdx.x;
    const int lane = t & 63, wave = t >> 6;
    const int wm = wave << 4;
    const int fr = lane & 15, fq = lane >> 4;
    const int m0 = blockIdx.y << 6, n0 = blockIdx.x << 6;
    const int koff = blockIdx.y & 7;

    // ---- phase 1: gate GEMM + o-rmsnorm + merge -> mh ----
    {
        f32x4 acc[4] = {};
        gemm_core64_lds(lds, vh, wgh, wgl, m0, n0, t, koff, acc);

        float rmsf[4];
#pragma unroll
        for (int r = 0; r < 4; ++r) {
            const int m = m0 + wm + (fq << 2) + r;
            float4 s4 = *(const float4*)&sumsq4[(size_t)m * 4];
            rmsf[r] = 1.f / sqrtf((s4.x + s4.y + s4.z + s4.w) * (1.f / 256.f) + 1e-6f);
        }
#pragma unroll
        for (int ni = 0; ni < 4; ++ni) {
            const int n  = n0 + (ni << 4) + fr;
            const int mb = m0 + wm + (fq << 2);
            const float bb  = bias[n];
            const float won = w_onorm[n];
#pragma unroll
            for (int r = 0; r < 4; ++r) {
                const int m = mb + r;
                const float g  = sigm(siluf(acc[ni][r] + bb));
                const float vv = __half2float(vh[(size_t)m * 256 + n]);
                const float oo = attn_o[(size_t)m * 256 + n] * rmsf[r] * won;
                mh[(size_t)m * 256 + n] = __float2half(g * vv + (1.f - g) * oo);
            }
        }
    }

    __threadfence();                       // device-scope release of mh
    cg::this_grid().sync();                // all blocks' mh visible
    __syncthreads();                       // LDS reuse fence (cheap)

    // ---- phase 2: out = silu(mh @ W_out) ----
    {
        f32x4 acc[4] = {};
        gemm_core64_lds(lds, mh, woh, wol, m0, n0, t, koff, acc);
#pragma unroll
        for (int ni = 0; ni < 4; ++ni) {
            const int n  = n0 + (ni << 4) + fr;
            const int mb = m0 + wm + (fq << 2);
#pragma unroll
            for (int r = 0; r < 4; ++r)
                out[(size_t)(mb + r) * 256 + n] = siluf(acc[ni][r]);
        }
    }
}

// =======================================================================
// Patch-GEMM local attention (R17 form: 8 B/lane staging, 2 barriers +
// own-wave lgkmcnt for PV).  Unchanged.
// =======================================================================
#define PT 216   // P / Vt row stride (halves)

__global__ __launch_bounds__(256, 2) void attn_mfma(
    const __half* __restrict__ qh, const __half* __restrict__ kh,
    const __half* __restrict__ vh, const float* __restrict__ width,
    const float* __restrict__ sharp, float* __restrict__ attn_o,
    float* __restrict__ sumsq4)
{
    __shared__ short smem[27648];          // 55296 B
    short* Ksh = smem;                     // [208][64] chunk-swizzled; overlaid by P [64][PT]
    short* Psh = smem;
    short* Vt  = smem + 13824;             // [64 d][PT]

    const int t = threadIdx.x;
    const int lane = t & 63, wave = t >> 6;
    const int fr = lane & 15, fq = lane >> 4;
    const int patch = blockIdx.x, h = blockIdx.y, b = blockIdx.z;
    const int pr0 = (patch >> 3) << 3, pc0 = (patch & 7) << 3;
    const int t0 = (wave * 28) >> 4;       // first n-tile of this wave's window

    float wd[4], sh[4]; int lq[4];
#pragma unroll
    for (int r = 0; r < 4; ++r) {
        const int q = (wave << 4) + (fq << 2) + r;
        lq[r] = (pr0 + (q >> 3)) * 64 + pc0 + (q & 7);
        wd[r] = width[((b << 12) + lq[r]) * 4 + h];
        sh[r] = sharp[((b << 12) + lq[r]) * 4 + h];
    }

    // ---- Q straight into A-frags ----
    const int qrow = (wave << 4) + fr;
    const int lqr = (pr0 + (qrow >> 3)) * 64 + pc0 + (qrow & 7);
    const __half* qptr = qh + (((size_t)(b << 12) + lqr) << 8) + (h << 6) + (fq << 3);
    half8 a0 = *(const half8*)qptr;
    half8 a1 = *(const half8*)(qptr + 32);

    // ---- K/V staging: 13 passes x 16 rows, 8 B/lane ----
    const int srow = t >> 4;               // row within pass
    const int d4 = (t & 15) << 2;          // 4 halves = 8 B per lane
    const size_t cbase = (((size_t)b << 12) * 256) + (size_t)h * 64 + d4;

    u32x2 kb2[13], vb2[13];
#pragma unroll
    for (int p = 0; p < 13; ++p) {
        const int prow = (p << 4) + srow;  // 0..207
        const int pi = prow / 14, pj = prow - pi * 14;
        const int gr = pr0 - 3 + pi, gc = pc0 - 3 + pj;
        const bool ok = (prow < 196) & ((unsigned)gr < 64u) & ((unsigned)gc < 64u);
        const int grc = min(max(gr, 0), 63), gcc = min(max(gc, 0), 63);
        const size_t off = cbase + (size_t)(grc * 64 + gcc) * 256;
        u32x2 kv = *(const u32x2*)(kh + off);
        u32x2 vv = *(const u32x2*)(vh + off);
        const u32x2 z = {0u, 0u};
        kb2[p] = ok ? kv : z;
        vb2[p] = ok ? vv : z;
    }

    const int chunk = d4 >> 3, dlo = d4 & 7;   // 8 B within one 16 B chunk
#pragma unroll
    for (int p = 0; p < 13; ++p) {
        const int prow = (p << 4) + srow;
        *(u32x2*)&Ksh[(prow << 6) + ((chunk ^ (prow & 7)) << 3) + dlo] = kb2[p];
        Vt[(d4)     * PT + prow] = (short)(vb2[p].x & 0xffffu);
        Vt[(d4 + 1) * PT + prow] = (short)(vb2[p].x >> 16);
        Vt[(d4 + 2) * PT + prow] = (short)(vb2[p].y & 0xffffu);
        Vt[(d4 + 3) * PT + prow] = (short)(vb2[p].y >> 16);
    }
    __syncthreads();

    // ---- QK^T: 8 windowed n-tiles of 16 positions ----
    f32x4 sc[8];
#pragma unroll
    for (int tl = 0; tl < 8; ++tl) {
        const int kr = ((t0 + tl) << 4) + fr;
        half8 b0 = *(const half8*)&Ksh[(kr << 6) + (((0 + fq) ^ (kr & 7)) << 3)];
        half8 b1 = *(const half8*)&Ksh[(kr << 6) + (((4 + fq) ^ (kr & 7)) << 3)];
        f32x4 z = {0.f, 0.f, 0.f, 0.f};
        z = __builtin_amdgcn_mfma_f32_16x16x32_f16(a0, b0, z, 0, 0, 0);
        sc[tl] = __builtin_amdgcn_mfma_f32_16x16x32_f16(a1, b1, z, 0, 0, 0);
    }

    // ---- mask + softmax ----
    float mx[4] = {-3e38f, -3e38f, -3e38f, -3e38f};
#pragma unroll
    for (int tl = 0; tl < 8; ++tl) {
        const int p = ((t0 + tl) << 4) + fr;
        const int pi = p / 14, pj = p - pi * 14;
        const bool pvld = p < 196;
#pragma unroll
        for (int r = 0; r < 4; ++r) {
            const int q = (wave << 4) + (fq << 2) + r;
            const int di = pi - 3 - ((q >> 3) & 7), dj = pj - 3 - (q & 7);
            const bool win = pvld & ((unsigned)(di + 3) <= 6u) & ((unsigned)(dj + 3) <= 6u);
            const float rel = sqrtf((float)(di * di + dj * dj));
            const float mk = sigm((wd[r] - rel) * sh[r]);
            float s = sc[tl][r] * 0.125f - (1.f - mk) * 10000.f;
            s = win ? s : -3e38f;
            sc[tl][r] = s;
            mx[r] = fmaxf(mx[r], s);
        }
    }
#pragma unroll
    for (int r = 0; r < 4; ++r) {
        mx[r] = fmaxf(mx[r], __shfl_xor(mx[r], 1));
        mx[r] = fmaxf(mx[r], __shfl_xor(mx[r], 2));
        mx[r] = fmaxf(mx[r], __shfl_xor(mx[r], 4));
        mx[r] = fmaxf(mx[r], __shfl_xor(mx[r], 8));
    }
    float sm[4] = {0.f, 0.f, 0.f, 0.f};
#pragma unroll
    for (int tl = 0; tl < 8; ++tl)
#pragma unroll
        for (int r = 0; r < 4; ++r) {
            const float e = __expf(sc[tl][r] - mx[r]);
            sc[tl][r] = e; sm[r] += e;
        }
#pragma unroll
    for (int r = 0; r < 4; ++r) {
        sm[r] += __shfl_xor(sm[r], 1);
        sm[r] += __shfl_xor(sm[r], 2);
        sm[r] += __shfl_xor(sm[r], 4);
        sm[r] += __shfl_xor(sm[r], 8);
        sm[r] = 1.f / sm[r];
    }

    __syncthreads();   // all waves' Ksh frag reads done before P overwrites
#pragma unroll
    for (int tl = 0; tl < 8; ++tl)
#pragma unroll
        for (int r = 0; r < 4; ++r) {
            __half pv = __float2half(sc[tl][r] * sm[r]);
            Psh[((wave << 4) + (fq << 2) + r) * PT + ((t0 + tl) << 4) + fr] = *(short*)&pv;
        }
    // PV reads only own-wave P rows + Vt (fenced by barrier #1):
    // own-wave LDS write->read ordering via lgkmcnt only.
    asm volatile("s_waitcnt lgkmcnt(0)" ::: "memory");
    __builtin_amdgcn_sched_barrier(0);

    // ---- PV: K = 128 (4x32), windowed at t0*16 ----
    f32x4 o[4] = {};
    const int pra = (wave << 4) + fr;
    const int cb = t0 << 4;
#pragma unroll
    for (int s = 0; s < 4; ++s) {
        half8 pa = *(const half8*)&Psh[pra * PT + cb + (fq << 3) + (s << 5)];
#pragma unroll
        for (int dt = 0; dt < 4; ++dt) {
            half8 vbf = *(const half8*)&Vt[((dt << 4) + fr) * PT + cb + (fq << 3) + (s << 5)];
            o[dt] = __builtin_amdgcn_mfma_f32_16x16x32_f16(pa, vbf, o[dt], 0, 0, 0);
        }
    }

#pragma unroll
    for (int r = 0; r < 4; ++r) {
        float ss = o[0][r]*o[0][r] + o[1][r]*o[1][r] + o[2][r]*o[2][r] + o[3][r]*o[3][r];
        ss += __shfl_xor(ss, 1); ss += __shfl_xor(ss, 2);
        ss += __shfl_xor(ss, 4); ss += __shfl_xor(ss, 8);
        const size_t rowb = (((size_t)(b << 12) + lq[r]) << 8) + h * 64;
#pragma unroll
        for (int dt = 0; dt < 4; ++dt)
            attn_o[rowb + (dt << 4) + fr] = o[dt][r];
        if (fr == 0) sumsq4[(((b << 12) + lq[r]) << 2) + h] = ss;
    }
}

extern "C" void kernel_launch(void* const* d_in, const int* in_sizes, int n_in,
                              void* d_out, int out_size, void* d_ws, size_t ws_size,
                              hipStream_t stream)
{
    const float* x      = (const float*)d_in[0];
    const float* W_qkv  = (const float*)d_in[1];
    const float* w_qn   = (const float*)d_in[2];
    const float* w_kn   = (const float*)d_in[3];
    const float* W_wp   = (const float*)d_in[4];
    const float* b_wp   = (const float*)d_in[5];
    const float* w_on   = (const float*)d_in[6];
    const float* W_out  = (const float*)d_in[7];
    const float* W_gate = (const float*)d_in[8];
    const float* b_gate = (const float*)d_in[9];
    float* out = (float*)d_out;

    __half* ws16 = (__half*)d_ws;
    __half* xh  = ws16;                    // [8][8192][32]
    __half* wqh = xh  + 2097152;           // [8][768][32]
    __half* wql = wqh + 196608;
    __half* wgh = wql + 196608;            // [8][256][32]
    __half* wgl = wgh + 65536;
    __half* woh = wgl + 65536;
    __half* wol = woh + 65536;
    __half* qhp = wol + 65536;             // [8192][256]
    __half* khp = qhp + 2097152;
    __half* vhp = khp + 2097152;
    __half* mh  = vhp + 2097152;
    float* attn_o = (float*)(mh + 2097152);  // [8192][256] f32
    float* widthp = attn_o + 2097152;
    float* sharpp = widthp + 32768;
    float* sumsq4 = sharpp + 32768;

    // x -> f16 blocked + wp; weights -> transposed f16 hi/lo blocked
    prep_kernel<<<304, 256, 0, stream>>>(x, W_qkv, W_gate, W_out, W_wp, b_wp,
                                         xh, wqh, wql, wgh, wgl, woh, wol,
                                         widthp, sharpp);
    // qkv GEMM (2-term, pipelined, k-staggered) + fused silu/rmsnorm/rope
    gemm_qkv<<<dim3(6, 128), 256, 0, stream>>>(xh, wqh, wql, w_qn, w_kn,
                                               qhp, khp, vhp);
    // patch-GEMM local attention (raw O + sumsq)
    attn_mfma<<<dim3(64, 4, 2), 256, 0, stream>>>(qhp, khp, vhp, widthp, sharpp,
                                                  attn_o, sumsq4);
    // cooperative fused gate+merge | grid.sync | out GEMM
    {
        const __half* vh_a = vhp;
        const __half* wgh_a = wgh; const __half* wgl_a = wgl;
        const float* bias_a = b_gate; const float* ao_a = attn_o;
        const float* ss_a = sumsq4; const float* won_a = w_on;
        __half* mh_a = mh;
        const __half* woh_a = woh; const __half* wol_a = wol;
        float* out_a = out;
        void* args[] = {(void*)&vh_a, (void*)&wgh_a, (void*)&wgl_a,
                        (void*)&bias_a, (void*)&ao_a, (void*)&ss_a,
                        (void*)&won_a, (void*)&mh_a, (void*)&woh_a,
                        (void*)&wol_a, (void*)&out_a};
        hipLaunchCooperativeKernel((void*)gemm_gateout, dim3(4, 128),
                                   dim3(256), args, 0, stream);
    }
}

// Round 15
// 131.489 us; speedup vs baseline: 2.1010x; 2.1010x over previous
//
#include <hip/hip_runtime.h>
#include <hip/hip_fp16.h>
#include <math.h>

__device__ __forceinline__ float sigm(float x)  { return 1.0f / (1.0f + __expf(-x)); }
__device__ __forceinline__ float siluf(float x) { return x * sigm(x); }

typedef _Float16 half8  __attribute__((ext_vector_type(8)));
typedef _Float16 half4  __attribute__((ext_vector_type(4)));
typedef float    f32x4  __attribute__((ext_vector_type(4)));
typedef unsigned u32x2  __attribute__((ext_vector_type(2)));

// async global->LDS, 16 B/lane: LDS dest = wave-uniform base + lane*16 (packed!)
__device__ __forceinline__ void gld16(const void* g, void* l) {
    __builtin_amdgcn_global_load_lds(
        (const __attribute__((address_space(1))) unsigned*)g,
        (__attribute__((address_space(3))) unsigned*)l, 16, 0, 0);
}

template <int N>
__device__ __forceinline__ void wait_vmcnt() {
    if constexpr (N == 0)      asm volatile("s_waitcnt vmcnt(0)" ::: "memory");
    else if constexpr (N == 3) asm volatile("s_waitcnt vmcnt(3)" ::: "memory");
    else if constexpr (N == 5) asm volatile("s_waitcnt vmcnt(5)" ::: "memory");
    else if constexpr (N == 6) asm volatile("s_waitcnt vmcnt(6)" ::: "memory");
}

// =======================================================================
// 2-term split GEMM core (2-buf counted-vmcnt, k-stagger).  Session local
// optimum: depth-2 (R10), fusion (R5/R11/R13), zero-LDS (R7), and
// drain-to-0 dbuf (R2) all regressed against this structure.
// =======================================================================
template <int MI, int AMODE>
__device__ __forceinline__ void gemm_core16(
    const __half* __restrict__ A16,
    const __half* __restrict__ Bhi, const __half* __restrict__ Blo,
    int nbs, int m0, int n0, int t, int koff, f32x4 (&acc)[MI][4])
{
    __shared__ short As[2][MI * 1024], BsHi[2][4096], BsLo[2][4096];
    const int lane = t & 63, wave = t >> 6;
    const int wm = (wave >> 1) * (MI << 4), wn = (wave & 1) << 6;
    const int fr = lane & 15, fq = lane >> 4;
    constexpr int NL = MI / 2 + 4;         // gld16s per wave per stage

    auto stage = [&](int kb, int buf) {
        const int kc = (kb + koff) & 7;    // staggered k-slice
#pragma unroll
        for (int hf = 0; hf < MI / 2; ++hf) {          // A: MI*8 rows/wave
            const int rr = wave * (MI << 3) + (hf << 4);
            size_t ga;
            if (AMODE == 0)
                ga = (((size_t)(kc * 8192 + m0 + rr)) << 5) + (lane << 3);
            else
                ga = (((size_t)(m0 + rr + (lane >> 2))) << 8) + (kc << 5) + ((lane & 3) << 3);
            gld16(A16 + ga, &As[buf][rr << 5]);
        }
#pragma unroll
        for (int hf = 0; hf < 2; ++hf) {               // B: 32 rows/wave
            const int rr = (wave << 5) + (hf << 4);
            const size_t gb = (((size_t)(kc * nbs + n0 + rr)) << 5) + (lane << 3);
            gld16(Bhi + gb, &BsHi[buf][rr << 5]);
            gld16(Blo + gb, &BsLo[buf][rr << 5]);
        }
    };

    stage(0, 0);
#pragma unroll
    for (int kb = 0; kb < 8; ++kb) {
        const int cur = kb & 1;
        if (kb < 7) {
            stage(kb + 1, cur ^ 1);        // NL loads now in flight
            wait_vmcnt<NL>();              // tile-k loads complete
        } else {
            wait_vmcnt<0>();
        }
        __builtin_amdgcn_s_barrier();      // all waves' tile-k writes visible

        half8 a[MI], bh[4], bl[4];
#pragma unroll
        for (int i = 0; i < MI; ++i)
            a[i] = *(const half8*)&As[cur][((wm + (i << 4) + fr) << 5) + (fq << 3)];
#pragma unroll
        for (int i = 0; i < 4; ++i) {
            const int boff = ((wn + (i << 4) + fr) << 5) + (fq << 3);
            bh[i] = *(const half8*)&BsHi[cur][boff];
            bl[i] = *(const half8*)&BsLo[cur][boff];
        }
#pragma unroll
        for (int mi = 0; mi < MI; ++mi)
#pragma unroll
            for (int ni = 0; ni < 4; ++ni) {
                acc[mi][ni] = __builtin_amdgcn_mfma_f32_16x16x32_f16(a[mi], bh[ni], acc[mi][ni], 0, 0, 0);
                acc[mi][ni] = __builtin_amdgcn_mfma_f32_16x16x32_f16(a[mi], bl[ni], acc[mi][ni], 0, 0, 0);
            }

        if (kb < 7) __builtin_amdgcn_s_barrier();
    }
}

// =======================================================================
// 64x64-tile core, 4 waves all in m; counted-vmcnt; k-stagger.
// =======================================================================
__device__ __forceinline__ void gemm_core64(
    const __half* __restrict__ A16,
    const __half* __restrict__ Bhi, const __half* __restrict__ Blo,
    int m0, int n0, int t, int koff, f32x4 (&acc)[4])
{
    __shared__ short As[2][2048], BsHi[2][2048], BsLo[2][2048];
    const int lane = t & 63, wave = t >> 6;
    const int wm = wave << 4;
    const int fr = lane & 15, fq = lane >> 4;

    auto stage = [&](int kb, int buf) {
        const int kc = (kb + koff) & 7;
        const int rr = wave << 4;          // 16 rows/wave (A and B)
        const size_t ga = (((size_t)(m0 + rr + (lane >> 2))) << 8) + (kc << 5) + ((lane & 3) << 3);
        gld16(A16 + ga, &As[buf][rr << 5]);
        const size_t gb = (((size_t)(kc * 256 + n0 + rr)) << 5) + (lane << 3);
        gld16(Bhi + gb, &BsHi[buf][rr << 5]);
        gld16(Blo + gb, &BsLo[buf][rr << 5]);
    };

    stage(0, 0);
#pragma unroll
    for (int kb = 0; kb < 8; ++kb) {
        const int cur = kb & 1;
        if (kb < 7) {
            stage(kb + 1, cur ^ 1);
            wait_vmcnt<3>();
        } else {
            wait_vmcnt<0>();
        }
        __builtin_amdgcn_s_barrier();

        half8 a = *(const half8*)&As[cur][((wm + fr) << 5) + (fq << 3)];
        half8 bh[4], bl[4];
#pragma unroll
        for (int ni = 0; ni < 4; ++ni) {
            const int boff = (((ni << 4) + fr) << 5) + (fq << 3);
            bh[ni] = *(const half8*)&BsHi[cur][boff];
            bl[ni] = *(const half8*)&BsLo[cur][boff];
        }
#pragma unroll
        for (int ni = 0; ni < 4; ++ni) {
            acc[ni] = __builtin_amdgcn_mfma_f32_16x16x32_f16(a, bh[ni], acc[ni], 0, 0, 0);
            acc[ni] = __builtin_amdgcn_mfma_f32_16x16x32_f16(a, bl[ni], acc[ni], 0, 0, 0);
        }

        if (kb < 7) __builtin_amdgcn_s_barrier();
    }
}

// =======================================================================
// Prep: x -> f16 k-blocked + wp; weights -> [kb][n][32] hi/lo.
// =======================================================================
__global__ __launch_bounds__(256) void prep_kernel(
    const float* __restrict__ x, const float* __restrict__ Wqkv,
    const float* __restrict__ Wgate, const float* __restrict__ Wout,
    const float* __restrict__ Wwp, const float* __restrict__ bwp,
    __half* __restrict__ xh,
    __half* __restrict__ wqh, __half* __restrict__ wql,
    __half* __restrict__ wgh, __half* __restrict__ wgl,
    __half* __restrict__ woh, __half* __restrict__ wol,
    float* __restrict__ width, float* __restrict__ sharp)
{
    __shared__ float xs[32][260];
    const int t = threadIdx.x;
    const int blk = blockIdx.x;
    if (blk < 256) {
        const int row0 = blk << 5;
        for (int e = t; e < 2048; e += 256) {
            int r = e >> 6, cc = (e & 63) << 2;
            *(float4*)&xs[r][cc] = *(const float4*)&x[(size_t)(row0 + r) * 256 + cc];
        }
        __syncthreads();
        const int r = t & 31, kb = t >> 5;
        __half hibuf[32];
#pragma unroll
        for (int i = 0; i < 32; ++i)
            hibuf[i] = __float2half(xs[r][(kb << 5) + i]);
        const size_t ob = ((size_t)(kb * 8192 + row0 + r)) << 5;
#pragma unroll
        for (int i = 0; i < 4; ++i)
            *(int4*)&xh[ob + (i << 3)] = *(int4*)&hibuf[i << 3];
        // wp: thread (r, n=kb); 4 accumulators break the 256-FMA dep chain
        float a0 = 0.f, a1 = 0.f, a2 = 0.f, a3 = 0.f;
#pragma unroll 4
        for (int k = 0; k < 256; k += 4) {
            a0 += xs[r][k + 0] * Wwp[(k + 0) * 8 + kb];
            a1 += xs[r][k + 1] * Wwp[(k + 1) * 8 + kb];
            a2 += xs[r][k + 2] * Wwp[(k + 2) * 8 + kb];
            a3 += xs[r][k + 3] * Wwp[(k + 3) * 8 + kb];
        }
        const float acc = (a0 + a1) + (a2 + a3);
        float s = sigm(siluf(acc + bwp[kb]));
        const int row = row0 + r;
        if (kb < 4) width[row * 4 + kb] = s * 4.242640687119285f + 0.5f;  // sqrt(18)
        else        sharp[row * 4 + kb - 4] = s * 9.5f + 0.5f;
    } else {
        const float* W; __half *Whi, *Wlo; int N, nb0, ncnt;
        if (blk < 288)      { W = Wqkv;  Whi = wqh; Wlo = wql; N = 768; nb0 = (blk - 256) * 24; ncnt = 24; }
        else if (blk < 296) { W = Wgate; Whi = wgh; Wlo = wgl; N = 256; nb0 = (blk - 288) * 32; ncnt = 32; }
        else                { W = Wout;  Whi = woh; Wlo = wol; N = 256; nb0 = (blk - 296) * 32; ncnt = 32; }
        for (int j = 0; j < ncnt; ++j)
            xs[j][t] = W[(size_t)t * N + nb0 + j];   // t = k row
        __syncthreads();
        for (int c = t; c < ncnt * 8; c += 256) {
            const int j = c >> 3, kb = c & 7;
            __half hibuf[32], lobuf[32];
#pragma unroll
            for (int i = 0; i < 32; ++i) {
                float v = xs[j][(kb << 5) + i];
                __half hv = __float2half(v);
                hibuf[i] = hv;
                lobuf[i] = __float2half(v - __half2float(hv));
            }
            const size_t ob = ((size_t)(kb * N + nb0 + j)) << 5;
#pragma unroll
            for (int i = 0; i < 4; ++i) {
                *(int4*)&Whi[ob + (i << 3)] = *(int4*)&hibuf[i << 3];
                *(int4*)&Wlo[ob + (i << 3)] = *(int4*)&lobuf[i << 3];
            }
        }
    }
}

// =======================================================================
// qkv GEMM (64x128 tiles, 768 blocks = 3/CU, k-staggered) + fused silu ->
// rmsnorm -> RoPE(pos=head) -> f16 stores.
// =======================================================================
__global__ __launch_bounds__(256, 3) void gemm_qkv(
    const __half* __restrict__ xh,
    const __half* __restrict__ wqh, const __half* __restrict__ wql,
    const float* __restrict__ wq, const float* __restrict__ wk,
    __half* __restrict__ qh, __half* __restrict__ kh, __half* __restrict__ vh)
{
    const int t  = threadIdx.x;
    const int m0 = blockIdx.y << 6, n0 = blockIdx.x << 7;
    f32x4 acc[2][4] = {};
    gemm_core16<2, 0>(xh, wqh, wql, 768, m0, n0, t, blockIdx.y & 7, acc);

    const int lane = t & 63, wave = t >> 6;
    const int wm = (wave >> 1) << 5, wn = (wave & 1) << 6;
    const int fr = lane & 15, fq = lane >> 4;
    const int gc0 = n0 + wn;
    const int seg = gc0 >> 8;          // 0=q, 1=k, 2=v
    const int h   = (gc0 >> 6) & 3;
    const int hc0 = h << 6;

#pragma unroll
    for (int mi = 0; mi < 2; ++mi)
#pragma unroll
        for (int ni = 0; ni < 4; ++ni)
#pragma unroll
            for (int r = 0; r < 4; ++r)
                acc[mi][ni][r] = siluf(acc[mi][ni][r]);

    if (seg == 2) {
#pragma unroll
        for (int mi = 0; mi < 2; ++mi)
#pragma unroll
            for (int r = 0; r < 4; ++r) {
                const size_t row = m0 + wm + (mi << 4) + (fq << 2) + r;
#pragma unroll
                for (int ni = 0; ni < 4; ++ni)
                    vh[row * 256 + hc0 + (ni << 4) + fr] = __float2half(acc[mi][ni][r]);
            }
    } else {
        const float* wnorm = seg ? wk : wq;
        float wv[4];
#pragma unroll
        for (int ni = 0; ni < 4; ++ni) wv[ni] = wnorm[(ni << 4) + fr];
        float cs[2], sn[2];
#pragma unroll
        for (int j = 0; j < 2; ++j) {
            const int d = (j << 4) + fr;
            const float freq = powf(10000.f, -(float)d * (1.f / 32.f));
            const float ang = (float)h * freq;    // pos = arange(H) reference quirk
            cs[j] = cosf(ang); sn[j] = sinf(ang);
        }
        __half* dstbase = (seg ? kh : qh);
#pragma unroll
        for (int mi = 0; mi < 2; ++mi)
#pragma unroll
            for (int r = 0; r < 4; ++r) {
                float ss = acc[mi][0][r] * acc[mi][0][r] + acc[mi][1][r] * acc[mi][1][r]
                         + acc[mi][2][r] * acc[mi][2][r] + acc[mi][3][r] * acc[mi][3][r];
                ss += __shfl_xor(ss, 1); ss += __shfl_xor(ss, 2);
                ss += __shfl_xor(ss, 4); ss += __shfl_xor(ss, 8);
                const float rinv = 1.f / sqrtf(ss * (1.f / 64.f) + 1e-6f);
                float xv[4];
#pragma unroll
                for (int ni = 0; ni < 4; ++ni) xv[ni] = acc[mi][ni][r] * rinv * wv[ni];
                const float o0 = xv[0] * cs[0] - xv[2] * sn[0];
                const float o2 = xv[0] * sn[0] + xv[2] * cs[0];
                const float o1 = xv[1] * cs[1] - xv[3] * sn[1];
                const float o3 = xv[1] * sn[1] + xv[3] * cs[1];
                const size_t row = m0 + wm + (mi << 4) + (fq << 2) + r;
                __half* dst = dstbase + row * 256 + hc0;
                dst[fr]      = __float2half(o0);
                dst[16 + fr] = __float2half(o1);
                dst[32 + fr] = __float2half(o2);
                dst[48 + fr] = __float2half(o3);
            }
    }
}

// ---- gate GEMM (64x64 tiles, 512 blocks, k-staggered) + o-rmsnorm + merge ----
__global__ __launch_bounds__(256, 2) void gemm_gate(
    const __half* __restrict__ vh,
    const __half* __restrict__ wgh, const __half* __restrict__ wgl,
    const float* __restrict__ bias, const float* __restrict__ attn_o,
    const float* __restrict__ sumsq4, const float* __restrict__ w_onorm,
    __half* __restrict__ mh)
{
    const int t  = threadIdx.x;
    const int m0 = blockIdx.y << 6, n0 = blockIdx.x << 6;
    f32x4 acc[4] = {};
    gemm_core64(vh, wgh, wgl, m0, n0, t, blockIdx.y & 7, acc);

    const int lane = t & 63, wave = t >> 6;
    const int wm = wave << 4;
    const int fr = lane & 15, fq = lane >> 4;

    float rmsf[4];
#pragma unroll
    for (int r = 0; r < 4; ++r) {
        const int m = m0 + wm + (fq << 2) + r;
        float4 s4 = *(const float4*)&sumsq4[(size_t)m * 4];
        rmsf[r] = 1.f / sqrtf((s4.x + s4.y + s4.z + s4.w) * (1.f / 256.f) + 1e-6f);
    }

#pragma unroll
    for (int ni = 0; ni < 4; ++ni) {
        const int n  = n0 + (ni << 4) + fr;
        const int mb = m0 + wm + (fq << 2);
        const float bb  = bias[n];
        const float won = w_onorm[n];
#pragma unroll
        for (int r = 0; r < 4; ++r) {
            const int m = mb + r;
            const float g  = sigm(siluf(acc[ni][r] + bb));
            const float vv = __half2float(vh[(size_t)m * 256 + n]);
            const float oo = attn_o[(size_t)m * 256 + n] * rmsf[r] * won;
            mh[(size_t)m * 256 + n] = __float2half(g * vv + (1.f - g) * oo);
        }
    }
}

// ---- final GEMM (64x64 tiles, 512 blocks, k-staggered): out = silu(mh @ W_out) ----
__global__ __launch_bounds__(256, 2) void gemm_out(
    const __half* __restrict__ mh,
    const __half* __restrict__ woh, const __half* __restrict__ wol,
    float* __restrict__ out)
{
    const int t  = threadIdx.x;
    const int m0 = blockIdx.y << 6, n0 = blockIdx.x << 6;
    f32x4 acc[4] = {};
    gemm_core64(mh, woh, wol, m0, n0, t, blockIdx.y & 7, acc);

    const int lane = t & 63, wave = t >> 6;
    const int wm = wave << 4;
    const int fr = lane & 15, fq = lane >> 4;
#pragma unroll
    for (int ni = 0; ni < 4; ++ni) {
        const int n  = n0 + (ni << 4) + fr;
        const int mb = m0 + wm + (fq << 2);
#pragma unroll
        for (int r = 0; r < 4; ++r)
            out[(size_t)(mb + r) * 256 + n] = siluf(acc[ni][r]);
    }
}

// =======================================================================
// Patch-GEMM local attention (8 B/lane staging, 2 barriers + own-wave
// lgkmcnt for PV).
// =======================================================================
#define PT 216   // P / Vt row stride (halves)

__global__ __launch_bounds__(256, 2) void attn_mfma(
    const __half* __restrict__ qh, const __half* __restrict__ kh,
    const __half* __restrict__ vh, const float* __restrict__ width,
    const float* __restrict__ sharp, float* __restrict__ attn_o,
    float* __restrict__ sumsq4)
{
    __shared__ short smem[27648];          // 55296 B
    short* Ksh = smem;                     // [208][64] chunk-swizzled; overlaid by P [64][PT]
    short* Psh = smem;
    short* Vt  = smem + 13824;             // [64 d][PT]

    const int t = threadIdx.x;
    const int lane = t & 63, wave = t >> 6;
    const int fr = lane & 15, fq = lane >> 4;
    const int patch = blockIdx.x, h = blockIdx.y, b = blockIdx.z;
    const int pr0 = (patch >> 3) << 3, pc0 = (patch & 7) << 3;
    const int t0 = (wave * 28) >> 4;       // first n-tile of this wave's window

    float wd[4], sh[4]; int lq[4];
#pragma unroll
    for (int r = 0; r < 4; ++r) {
        const int q = (wave << 4) + (fq << 2) + r;
        lq[r] = (pr0 + (q >> 3)) * 64 + pc0 + (q & 7);
        wd[r] = width[((b << 12) + lq[r]) * 4 + h];
        sh[r] = sharp[((b << 12) + lq[r]) * 4 + h];
    }

    // ---- Q straight into A-frags ----
    const int qrow = (wave << 4) + fr;
    const int lqr = (pr0 + (qrow >> 3)) * 64 + pc0 + (qrow & 7);
    const __half* qptr = qh + (((size_t)(b << 12) + lqr) << 8) + (h << 6) + (fq << 3);
    half8 a0 = *(const half8*)qptr;
    half8 a1 = *(const half8*)(qptr + 32);

    // ---- K/V staging: 13 passes x 16 rows, 8 B/lane ----
    const int srow = t >> 4;               // row within pass
    const int d4 = (t & 15) << 2;          // 4 halves = 8 B per lane
    const size_t cbase = (((size_t)b << 12) * 256) + (size_t)h * 64 + d4;

    u32x2 kb2[13], vb2[13];
#pragma unroll
    for (int p = 0; p < 13; ++p) {
        const int prow = (p << 4) + srow;  // 0..207
        const int pi = prow / 14, pj = prow - pi * 14;
        const int gr = pr0 - 3 + pi, gc = pc0 - 3 + pj;
        const bool ok = (prow < 196) & ((unsigned)gr < 64u) & ((unsigned)gc < 64u);
        const int grc = min(max(gr, 0), 63), gcc = min(max(gc, 0), 63);
        const size_t off = cbase + (size_t)(grc * 64 + gcc) * 256;
        u32x2 kv = *(const u32x2*)(kh + off);
        u32x2 vv = *(const u32x2*)(vh + off);
        const u32x2 z = {0u, 0u};
        kb2[p] = ok ? kv : z;
        vb2[p] = ok ? vv : z;
    }

    const int chunk = d4 >> 3, dlo = d4 & 7;   // 8 B within one 16 B chunk
#pragma unroll
    for (int p = 0; p < 13; ++p) {
        const int prow = (p << 4) + srow;
        *(u32x2*)&Ksh[(prow << 6) + ((chunk ^ (prow & 7)) << 3) + dlo] = kb2[p];
        Vt[(d4)     * PT + prow] = (short)(vb2[p].x & 0xffffu);
        Vt[(d4 + 1) * PT + prow] = (short)(vb2[p].x >> 16);
        Vt[(d4 + 2) * PT + prow] = (short)(vb2[p].y & 0xffffu);
        Vt[(d4 + 3) * PT + prow] = (short)(vb2[p].y >> 16);
    }
    __syncthreads();

    // ---- QK^T: 8 windowed n-tiles of 16 positions ----
    f32x4 sc[8];
#pragma unroll
    for (int tl = 0; tl < 8; ++tl) {
        const int kr = ((t0 + tl) << 4) + fr;
        half8 b0 = *(const half8*)&Ksh[(kr << 6) + (((0 + fq) ^ (kr & 7)) << 3)];
        half8 b1 = *(const half8*)&Ksh[(kr << 6) + (((4 + fq) ^ (kr & 7)) << 3)];
        f32x4 z = {0.f, 0.f, 0.f, 0.f};
        z = __builtin_amdgcn_mfma_f32_16x16x32_f16(a0, b0, z, 0, 0, 0);
        sc[tl] = __builtin_amdgcn_mfma_f32_16x16x32_f16(a1, b1, z, 0, 0, 0);
    }

    // ---- mask + softmax ----
    float mx[4] = {-3e38f, -3e38f, -3e38f, -3e38f};
#pragma unroll
    for (int tl = 0; tl < 8; ++tl) {
        const int p = ((t0 + tl) << 4) + fr;
        const int pi = p / 14, pj = p - pi * 14;
        const bool pvld = p < 196;
#pragma unroll
        for (int r = 0; r < 4; ++r) {
            const int q = (wave << 4) + (fq << 2) + r;
            const int di = pi - 3 - ((q >> 3) & 7), dj = pj - 3 - (q & 7);
            const bool win = pvld & ((unsigned)(di + 3) <= 6u) & ((unsigned)(dj + 3) <= 6u);
            const float rel = sqrtf((float)(di * di + dj * dj));
            const float mk = sigm((wd[r] - rel) * sh[r]);
            float s = sc[tl][r] * 0.125f - (1.f - mk) * 10000.f;
            s = win ? s : -3e38f;
            sc[tl][r] = s;
            mx[r] = fmaxf(mx[r], s);
        }
    }
#pragma unroll
    for (int r = 0; r < 4; ++r) {
        mx[r] = fmaxf(mx[r], __shfl_xor(mx[r], 1));
        mx[r] = fmaxf(mx[r], __shfl_xor(mx[r], 2));
        mx[r] = fmaxf(mx[r], __shfl_xor(mx[r], 4));
        mx[r] = fmaxf(mx[r], __shfl_xor(mx[r], 8));
    }
    float sm[4] = {0.f, 0.f, 0.f, 0.f};
#pragma unroll
    for (int tl = 0; tl < 8; ++tl)
#pragma unroll
        for (int r = 0; r < 4; ++r) {
            const float e = __expf(sc[tl][r] - mx[r]);
            sc[tl][r] = e; sm[r] += e;
        }
#pragma unroll
    for (int r = 0; r < 4; ++r) {
        sm[r] += __shfl_xor(sm[r], 1);
        sm[r] += __shfl_xor(sm[r], 2);
        sm[r] += __shfl_xor(sm[r], 4);
        sm[r] += __shfl_xor(sm[r], 8);
        sm[r] = 1.f / sm[r];
    }

    __syncthreads();   // all waves' Ksh frag reads done before P overwrites
#pragma unroll
    for (int tl = 0; tl < 8; ++tl)
#pragma unroll
        for (int r = 0; r < 4; ++r) {
            __half pv = __float2half(sc[tl][r] * sm[r]);
            Psh[((wave << 4) + (fq << 2) + r) * PT + ((t0 + tl) << 4) + fr] = *(short*)&pv;
        }
    // PV reads only own-wave P rows + Vt (fenced by barrier #1):
    // own-wave LDS write->read ordering via lgkmcnt only.
    asm volatile("s_waitcnt lgkmcnt(0)" ::: "memory");
    __builtin_amdgcn_sched_barrier(0);

    // ---- PV: K = 128 (4x32), windowed at t0*16 ----
    f32x4 o[4] = {};
    const int pra = (wave << 4) + fr;
    const int cb = t0 << 4;
#pragma unroll
    for (int s = 0; s < 4; ++s) {
        half8 pa = *(const half8*)&Psh[pra * PT + cb + (fq << 3) + (s << 5)];
#pragma unroll
        for (int dt = 0; dt < 4; ++dt) {
            half8 vbf = *(const half8*)&Vt[((dt << 4) + fr) * PT + cb + (fq << 3) + (s << 5)];
            o[dt] = __builtin_amdgcn_mfma_f32_16x16x32_f16(pa, vbf, o[dt], 0, 0, 0);
        }
    }

#pragma unroll
    for (int r = 0; r < 4; ++r) {
        float ss = o[0][r]*o[0][r] + o[1][r]*o[1][r] + o[2][r]*o[2][r] + o[3][r]*o[3][r];
        ss += __shfl_xor(ss, 1); ss += __shfl_xor(ss, 2);
        ss += __shfl_xor(ss, 4); ss += __shfl_xor(ss, 8);
        const size_t rowb = (((size_t)(b << 12) + lq[r]) << 8) + h * 64;
#pragma unroll
        for (int dt = 0; dt < 4; ++dt)
            attn_o[rowb + (dt << 4) + fr] = o[dt][r];
        if (fr == 0) sumsq4[(((b << 12) + lq[r]) << 2) + h] = ss;
    }
}

extern "C" void kernel_launch(void* const* d_in, const int* in_sizes, int n_in,
                              void* d_out, int out_size, void* d_ws, size_t ws_size,
                              hipStream_t stream)
{
    const float* x      = (const float*)d_in[0];
    const float* W_qkv  = (const float*)d_in[1];
    const float* w_qn   = (const float*)d_in[2];
    const float* w_kn   = (const float*)d_in[3];
    const float* W_wp   = (const float*)d_in[4];
    const float* b_wp   = (const float*)d_in[5];
    const float* w_on   = (const float*)d_in[6];
    const float* W_out  = (const float*)d_in[7];
    const float* W_gate = (const float*)d_in[8];
    const float* b_gate = (const float*)d_in[9];
    float* out = (float*)d_out;

    __half* ws16 = (__half*)d_ws;
    __half* xh  = ws16;                    // [8][8192][32]
    __half* wqh = xh  + 2097152;           // [8][768][32]
    __half* wql = wqh + 196608;
    __half* wgh = wql + 196608;            // [8][256][32]
    __half* wgl = wgh + 65536;
    __half* woh = wgl + 65536;
    __half* wol = woh + 65536;
    __half* qhp = wol + 65536;             // [8192][256]
    __half* khp = qhp + 2097152;
    __half* vhp = khp + 2097152;
    __half* mh  = vhp + 2097152;
    float* attn_o = (float*)(mh + 2097152);  // [8192][256] f32
    float* widthp = attn_o + 2097152;
    float* sharpp = widthp + 32768;
    float* sumsq4 = sharpp + 32768;

    // x -> f16 blocked + wp; weights -> transposed f16 hi/lo blocked
    prep_kernel<<<304, 256, 0, stream>>>(x, W_qkv, W_gate, W_out, W_wp, b_wp,
                                         xh, wqh, wql, wgh, wgl, woh, wol,
                                         widthp, sharpp);
    // qkv GEMM (2-term, pipelined, k-staggered) + fused silu/rmsnorm/rope
    gemm_qkv<<<dim3(6, 128), 256, 0, stream>>>(xh, wqh, wql, w_qn, w_kn,
                                               qhp, khp, vhp);
    // patch-GEMM local attention (raw O + sumsq)
    attn_mfma<<<dim3(64, 4, 2), 256, 0, stream>>>(qhp, khp, vhp, widthp, sharpp,
                                                  attn_o, sumsq4);
    // gate gemm (64x64, 512 blocks, k-staggered) + fused o-rmsnorm + merge
    gemm_gate<<<dim3(4, 128), 256, 0, stream>>>(vhp, wgh, wgl, b_gate,
                                                attn_o, sumsq4, w_on, mh);
    // final silu(merged @ W_out) (64x64, 512 blocks, k-staggered)
    gemm_out<<<dim3(4, 128), 256, 0, stream>>>(mh, woh, wol, out);
}